// Round 16
// baseline (814.392 us; speedup 1.0000x reference)
//
#include <hip/hip_runtime.h>
#include <hip/hip_cooperative_groups.h>
#include <math.h>
#include <stdint.h>

namespace cg = cooperative_groups;

#define N_NODES 10000
#define N_EDGES 160000
#define F 128
#define NB 8
#define HR 64
#define NSPEC 10
#define PI_F 3.14159265358979323846f
#define NPAD 10160
#define NT_MAX 635
#define ETILES 2500
#define CBLK 512                 // cooperative grid blocks
#define GT (CBLK*256)            // cooperative grid threads

typedef unsigned short ushort_t;
typedef __attribute__((ext_vector_type(8))) short short8;
typedef __attribute__((ext_vector_type(4))) float f32x4;

__device__ __forceinline__ float silu_f(float x){ return x / (1.f + expf(-x)); }
__device__ __forceinline__ float bfu(ushort_t u) {
    union { unsigned int i; float f; } v; v.i = ((unsigned int)u) << 16; return v.f;
}
__device__ __forceinline__ ushort_t f2bf(float f) {
    union { float f; unsigned int i; } v; v.f = f;
    unsigned int x = v.i;
    unsigned int r = (x + 0x7fffu + ((x >> 16) & 1u)) >> 16;
    return (ushort_t)r;
}

// ================= kernel 1: cooperative setup =================
struct SetupArgs {
    const float* vectors; const int* spec; const int* senders; const int* receivers;
    const float* embW; const float* rW2; const float* linW; const float* scW;
    ushort_t* WBlin0; ushort_t* WBsc0; ushort_t* W2T0;
    int* zero_base;          // counts(10000), cursor(10000), scnt(16), scur(16) contiguous
    int* counts; int* cursor; int* scnt; int* scur;
    int* sptr; int* psptr; int* tile_spec;
    int* perm; int* inv; int* specS; int* pn;
    int* row_ptr; int* sndrow;
    float* basis_pos; ushort_t* fB0;
};

__global__ __launch_bounds__(256) void k_setup(SetupArgs A)
{
    cg::grid_group grid = cg::this_grid();
    const int t = threadIdx.x;
    const int gtid = blockIdx.x*256 + t;

    // ---- P0: zero counters + convert weights ----
    for (int i = gtid; i < 2*N_NODES + 32; i += GT) A.zero_base[i] = 0;
    {
        const int LINTOT = 2*NSPEC*16384;
        const int SCTOT  = NSPEC*16384;
        const int CONVTOT = LINTOT + SCTOT + 2*128*64;
        for (int i = gtid; i < CONVTOT; i += GT) {
            if (i < LINTOT) {
                int mat = i >> 14;
                int r = i & 16383;
                int fo = r >> 7, fi = r & 127;
                A.WBlin0[(size_t)mat*16384 + fo*128 + fi] =
                    f2bf(A.linW[((size_t)mat*4 + 0)*16384 + fi*128 + fo]);
            } else if (i < LINTOT + SCTOT) {
                int t2 = i - LINTOT;
                int sp = t2 >> 14;
                int r = t2 & 16383;
                int fo = r >> 7, fi = r & 127;
                A.WBsc0[(size_t)sp*16384 + fo*128 + fi] =
                    f2bf(A.scW[((size_t)(NSPEC + sp)*4 + 0)*16384 + fi*128 + fo]);
            } else {
                int t2 = i - LINTOT - SCTOT;
                int l = t2 >> 13; int r = t2 & 8191; int f = r >> 6; int k = r & 63;
                A.W2T0[t2] = f2bf(A.rW2[(size_t)l*HR*512 + (size_t)k*512 + 4*f]);
            }
        }
    }
    grid.sync();

    // ---- P1: histograms (raw node ids for counts) ----
    for (int n = gtid; n < N_NODES; n += GT) atomicAdd(&A.scnt[A.spec[n]], 1);
    for (int e = gtid; e < N_EDGES; e += GT) atomicAdd(&A.counts[A.receivers[e]], 1);
    grid.sync();

    // ---- P2: species scan (single thread) ----
    if (gtid == 0) {
        int acc = 0, pacc = 0;
        for (int s = 0; s < NSPEC; ++s) {
            A.sptr[s] = acc; A.psptr[s] = pacc;
            acc += A.scnt[s];
            pacc += ((A.scnt[s] + 15) >> 4) << 4;
        }
        A.sptr[NSPEC] = acc; A.psptr[NSPEC] = pacc;
        for (int tt = 0; tt < NT_MAX; ++tt) A.tile_spec[tt] = -1;
        for (int s = 0; s < NSPEC; ++s) {
            int t0 = A.psptr[s] >> 4;
            int t1 = t0 + ((A.scnt[s] + 15) >> 4);
            for (int tt = t0; tt < t1; ++tt) A.tile_spec[tt] = s;
        }
    }
    grid.sync();

    // ---- P3: sort fill ----
    for (int n = gtid; n < N_NODES; n += GT) {
        int s = A.spec[n];
        int pos = A.sptr[s] + atomicAdd(&A.scur[s], 1);
        A.perm[pos] = n; A.inv[n] = pos; A.specS[pos] = s;
        A.pn[pos] = A.psptr[s] + (pos - A.sptr[s]);
    }
    grid.sync();

    // ---- P4: row_ptr scan over sorted nodes (block 0 only) ----
    __shared__ int ps[256];
    if (blockIdx.x == 0) {
        int loc[40];
        int sum = 0;
        int base = t * 40;
        #pragma unroll
        for (int j = 0; j < 40; ++j) {
            int idx = base + j;
            int c = (idx < N_NODES) ? A.counts[A.perm[idx]] : 0;
            loc[j] = c; sum += c;
        }
        ps[t] = sum;
        __syncthreads();
        for (int off = 1; off < 256; off <<= 1) {
            int v = (t >= off) ? ps[t-off] : 0;
            __syncthreads();
            ps[t] += v;
            __syncthreads();
        }
        int ex = ps[t] - sum;
        #pragma unroll
        for (int j = 0; j < 40; ++j) {
            int idx = base + j;
            if (idx < N_NODES) A.row_ptr[idx] = ex;
            ex += loc[j];
        }
        if (t == 255) A.row_ptr[N_NODES] = ex;
    }
    grid.sync();

    // ---- P5: CSR fill + basis + sender rows; emb init ----
    for (int e = gtid; e < N_EDGES; e += GT) {
        int r = A.inv[A.receivers[e]];
        int q = A.row_ptr[r] + atomicAdd(&A.cursor[r], 1);
        A.sndrow[q] = A.pn[A.inv[A.senders[e]]];
        float x = A.vectors[e*3+0], y = A.vectors[e*3+1], z = A.vectors[e*3+2];
        float rr = sqrtf(x*x + y*y + z*z);
        rr = fmaxf(rr, 1e-9f);
        float rc = fminf(rr, 5.0f);
        float cut = 0.5f * (cosf(PI_F * rc * 0.2f) + 1.f);
        float pref = sqrtf(0.4f) * cut / rr;
        float B[8];
        #pragma unroll
        for (int k = 1; k <= 8; ++k) B[k-1] = pref * sinf(PI_F * 0.2f * (float)k * rr);
        float4* dst = (float4*)(A.basis_pos + (size_t)q*8);
        dst[0] = make_float4(B[0], B[1], B[2], B[3]);
        dst[1] = make_float4(B[4], B[5], B[6], B[7]);
    }
    for (int i = gtid; i < N_NODES*F; i += GT) {
        int n = i >> 7, f = i & 127;
        A.fB0[(size_t)A.pn[n]*128 + f] = f2bf(A.embW[A.specS[n]*F + f]);
    }
}

// ================= kernel 2: edge-parallel radial MLP (both layers) =================
// 2500 blocks x 256; wave wv owns 16 positions; no inter-phase barriers (per-wave hB)
__global__ __launch_bounds__(256) void k_rw(
    const float* __restrict__ basis_pos,
    const float* __restrict__ rW1,
    const float* __restrict__ rb1,
    const ushort_t* __restrict__ W2T0,
    ushort_t* __restrict__ rw0)
{
    __shared__ float W1s[2][NB*HR];
    __shared__ float b1s[2][HR];
    __shared__ ushort_t hB[4][16][72];

    const int t = threadIdx.x;
    const int wv = t >> 6;
    const int lane = t & 63;
    const int j64 = lane;
    const int r16 = lane & 15;
    const int quad = lane >> 4;

    W1s[0][t] = rW1[t];       W1s[0][256 + t] = rW1[256 + t];
    W1s[1][t] = rW1[512 + t]; W1s[1][256 + t] = rW1[768 + t];
    if (t < HR) { b1s[0][t] = rb1[t]; b1s[1][t] = rb1[HR + t]; }

    const int p0 = blockIdx.x * 64 + wv * 16;
    __syncthreads();

    for (int l = 0; l < 2; ++l) {
        // phase A: h (bf16) — per-wave private LDS
        #pragma unroll 4
        for (int e = 0; e < 16; ++e) {
            const float4* B4 = (const float4*)(basis_pos + (size_t)(p0 + e)*8);
            float4 x0 = B4[0], x1 = B4[1];
            float a = b1s[l][j64];
            a = fmaf(x0.x, W1s[l][0*HR + j64], a);
            a = fmaf(x0.y, W1s[l][1*HR + j64], a);
            a = fmaf(x0.z, W1s[l][2*HR + j64], a);
            a = fmaf(x0.w, W1s[l][3*HR + j64], a);
            a = fmaf(x1.x, W1s[l][4*HR + j64], a);
            a = fmaf(x1.y, W1s[l][5*HR + j64], a);
            a = fmaf(x1.z, W1s[l][6*HR + j64], a);
            a = fmaf(x1.w, W1s[l][7*HR + j64], a);
            hB[wv][e][j64] = f2bf(a / (1.f + expf(-a)));
        }
        // phase B: MFMA rw0_l = h(16x64) @ W2_l0(64x128)
        {
            short8 a0 = *(const short8*)&hB[wv][r16][quad*8];
            short8 a1 = *(const short8*)&hB[wv][r16][32 + quad*8];
            const ushort_t* W2l = W2T0 + l*8192;
            ushort_t* dst = rw0 + (size_t)l*N_EDGES*128;
            #pragma unroll
            for (int nt = 0; nt < 8; ++nt) {
                const int col = nt*16 + r16;
                short8 b0 = *(const short8*)(W2l + (size_t)col*64 + quad*8);
                short8 b1 = *(const short8*)(W2l + (size_t)col*64 + 32 + quad*8);
                f32x4 c = (f32x4){0.f, 0.f, 0.f, 0.f};
                c = __builtin_amdgcn_mfma_f32_16x16x32_bf16(a0, b0, c, 0, 0, 0);
                c = __builtin_amdgcn_mfma_f32_16x16x32_bf16(a1, b1, c, 0, 0, 0);
                #pragma unroll
                for (int r = 0; r < 4; ++r)
                    dst[(size_t)(p0 + quad*4 + r)*128 + col] = f2bf(c[r]);
            }
        }
    }
}

// ================= kernel 3: cooperative main =================
struct MainArgs {
    const int* row_ptr; const int* sndrow; const int* pn;
    const ushort_t* rw0;
    const ushort_t* WBlin0; const ushort_t* WBsc0;
    const int* tile_spec; const int* scnt; const int* sptr; const int* psptr; const int* perm;
    const float* prodc; const float* ro0; const float* ro1W1; const float* ro1W2;
    ushort_t* fB0; ushort_t* fB1; ushort_t* aggB0;
    float* out;
};

__global__ __launch_bounds__(256) void k_main(MainArgs A)
{
    cg::grid_group grid = cg::this_grid();
    __shared__ float redS[16][65];
    __shared__ float sS[16][132];
    __shared__ float yS[16][17];

    const int t = threadIdx.x;
    const int lane = t & 63;
    const int wv = t >> 6;
    const int r16 = lane & 15;
    const int quad = lane >> 4;

    // ---- PA: agg layer 0 ----
    for (int v = blockIdx.x; v < N_NODES/2; v += CBLK) {
        const int n = v*2 + (t >> 7);
        const int f = t & 127;
        const int p0 = A.row_ptr[n], p1 = A.row_ptr[n+1];
        float acc = 0.f;
        #pragma unroll 4
        for (int p = p0; p < p1; ++p) {
            const float sf = bfu(A.fB0[(size_t)A.sndrow[p]*128 + f]);
            const float rl = bfu(A.rw0[(size_t)p*128 + f]);
            acc = fmaf(sf, rl, acc);
        }
        A.aggB0[(size_t)A.pn[n]*128 + f] = f2bf(acc);
    }
    grid.sync();

    // ---- PB: gemm_epi0 (lin GEMM + poly + fB1 + readout0), grid-stride over tiles ----
    for (int tile = blockIdx.x; tile < NT_MAX; tile += CBLK) {
        const int spec = A.tile_spec[tile];
        if (spec >= 0) {
            const ushort_t* Ap = A.aggB0 + (size_t)tile*16*128;
            const ushort_t* Wp = A.WBlin0 + (size_t)spec*16384;
            const float* pc = A.prodc + (size_t)spec*3*F;
            short8 a[4];
            #pragma unroll
            for (int c = 0; c < 4; ++c)
                a[c] = *(const short8*)(Ap + (size_t)r16*128 + c*32 + quad*8);
            float pr[4] = {0.f, 0.f, 0.f, 0.f};
            #pragma unroll
            for (int nt = 0; nt < 2; ++nt) {
                const int col = wv*32 + nt*16 + r16;
                f32x4 acc = (f32x4){0.f, 0.f, 0.f, 0.f};
                #pragma unroll
                for (int c = 0; c < 4; ++c) {
                    short8 b = *(const short8*)(Wp + (size_t)col*128 + c*32 + quad*8);
                    acc = __builtin_amdgcn_mfma_f32_16x16x32_bf16(a[c], b, acc, 0, 0, 0);
                }
                const float w0 = A.ro0[col];
                const float p0c = pc[col], p1c = pc[F+col], p2c = pc[2*F+col];
                #pragma unroll
                for (int r = 0; r < 4; ++r) {
                    float s = acc[r] * 0.5f;
                    float val = s * (p0c + p1c*s + p2c*s*s);
                    A.fB1[((size_t)tile*16 + quad*4 + r)*128 + col] = f2bf(val);
                    pr[r] = fmaf(val, w0, pr[r]);
                }
            }
            #pragma unroll
            for (int r = 0; r < 4; ++r) redS[quad*4 + r][wv*16 + r16] = pr[r];
            __syncthreads();
            if (t < 16) {
                int rel = tile*16 + t - A.psptr[spec];
                if (rel < A.scnt[spec]) {
                    float s = 0.f;
                    for (int j = 0; j < 64; ++j) s += redS[t][j];
                    A.out[(size_t)A.perm[A.sptr[spec] + rel]*2 + 0] = s;
                }
            }
            __syncthreads();   // protect redS before next tile iteration
        }
    }
    grid.sync();

    // ---- PC: agg layer 1 ----
    {
        const ushort_t* rw1l = A.rw0 + (size_t)N_EDGES*128;
        for (int v = blockIdx.x; v < N_NODES/2; v += CBLK) {
            const int n = v*2 + (t >> 7);
            const int f = t & 127;
            const int p0 = A.row_ptr[n], p1 = A.row_ptr[n+1];
            float acc = 0.f;
            #pragma unroll 4
            for (int p = p0; p < p1; ++p) {
                const float sf = bfu(A.fB1[(size_t)A.sndrow[p]*128 + f]);
                const float rl = bfu(rw1l[(size_t)p*128 + f]);
                acc = fmaf(sf, rl, acc);
            }
            A.aggB0[(size_t)A.pn[n]*128 + f] = f2bf(acc);
        }
    }
    grid.sync();

    // ---- PD: gemm_epi1 (lin+sc GEMM + poly + MLP readout1), grid-stride over tiles ----
    for (int tile = blockIdx.x; tile < NT_MAX; tile += CBLK) {
        const int spec = A.tile_spec[tile];
        if (spec >= 0) {
            const ushort_t* Ap = A.aggB0 + (size_t)tile*16*128;
            const ushort_t* Fp = A.fB1   + (size_t)tile*16*128;
            const ushort_t* Wl = A.WBlin0 + (size_t)(NSPEC + spec)*16384;
            const ushort_t* Ws = A.WBsc0  + (size_t)spec*16384;
            const float* pc = A.prodc + ((size_t)NSPEC + spec)*3*F;
            short8 a1[4], a2[4];
            #pragma unroll
            for (int c = 0; c < 4; ++c) {
                a1[c] = *(const short8*)(Ap + (size_t)r16*128 + c*32 + quad*8);
                a2[c] = *(const short8*)(Fp + (size_t)r16*128 + c*32 + quad*8);
            }
            #pragma unroll
            for (int nt = 0; nt < 2; ++nt) {
                const int col = wv*32 + nt*16 + r16;
                f32x4 accl = (f32x4){0.f, 0.f, 0.f, 0.f};
                f32x4 accs = (f32x4){0.f, 0.f, 0.f, 0.f};
                #pragma unroll
                for (int c = 0; c < 4; ++c) {
                    short8 bl = *(const short8*)(Wl + (size_t)col*128 + c*32 + quad*8);
                    short8 bs = *(const short8*)(Ws + (size_t)col*128 + c*32 + quad*8);
                    accl = __builtin_amdgcn_mfma_f32_16x16x32_bf16(a1[c], bl, accl, 0, 0, 0);
                    accs = __builtin_amdgcn_mfma_f32_16x16x32_bf16(a2[c], bs, accs, 0, 0, 0);
                }
                const float p0c = pc[col], p1c = pc[F+col], p2c = pc[2*F+col];
                #pragma unroll
                for (int r = 0; r < 4; ++r) {
                    float s = accl[r] * 0.5f;
                    sS[quad*4 + r][col] = s * (p0c + p1c*s + p2c*s*s) + accs[r];
                }
            }
            __syncthreads();
            {
                const int node = t >> 4, c = t & 15;
                float a = 0.f;
                #pragma unroll 8
                for (int g = 0; g < F; ++g) a = fmaf(sS[node][g], A.ro1W1[g*16 + c], a);
                a = silu_f(a);
                yS[node][c] = a * A.ro1W2[c];
            }
            __syncthreads();
            if (t < 16) {
                int rel = tile*16 + t - A.psptr[spec];
                if (rel < A.scnt[spec]) {
                    float s = 0.f;
                    #pragma unroll
                    for (int j = 0; j < 16; ++j) s += yS[t][j];
                    A.out[(size_t)A.perm[A.sptr[spec] + rel]*2 + 1] = s;
                }
            }
            __syncthreads();   // protect sS/yS before next tile iteration
        }
    }
}

extern "C" void kernel_launch(void* const* d_in, const int* in_sizes, int n_in,
                              void* d_out, int out_size, void* d_ws, size_t ws_size,
                              hipStream_t stream)
{
    (void)in_sizes; (void)n_in; (void)out_size; (void)ws_size;
    const float* vectors   = (const float*)d_in[0];
    const int*   spec      = (const int*)d_in[1];
    const int*   senders   = (const int*)d_in[2];
    const int*   receivers = (const int*)d_in[3];
    const float* embW      = (const float*)d_in[4];
    const float* rW1       = (const float*)d_in[5];
    const float* rb1       = (const float*)d_in[6];
    const float* rW2       = (const float*)d_in[7];
    const float* linW      = (const float*)d_in[8];
    const float* prodc     = (const float*)d_in[9];
    const float* scW       = (const float*)d_in[10];
    const float* ro0       = (const float*)d_in[11];
    const float* ro1W1     = (const float*)d_in[12];
    const float* ro1W2     = (const float*)d_in[13];
    float* out = (float*)d_out;

    char* ws = (char*)d_ws;
    float*    basis_pos = (float*)ws;    ws += sizeof(float)*(size_t)N_EDGES*8;
    ushort_t* rw0       = (ushort_t*)ws; ws += sizeof(ushort_t)*(size_t)2*N_EDGES*128;
    ushort_t* fB0       = (ushort_t*)ws; ws += sizeof(ushort_t)*(size_t)NPAD*128;
    ushort_t* fB1       = (ushort_t*)ws; ws += sizeof(ushort_t)*(size_t)NPAD*128;
    ushort_t* aggB0     = (ushort_t*)ws; ws += sizeof(ushort_t)*(size_t)NPAD*128;
    ushort_t* WBlin0    = (ushort_t*)ws; ws += sizeof(ushort_t)*(size_t)2*NSPEC*16384;
    ushort_t* WBsc0     = (ushort_t*)ws; ws += sizeof(ushort_t)*(size_t)NSPEC*16384;
    ushort_t* W2T0      = (ushort_t*)ws; ws += sizeof(ushort_t)*(size_t)2*128*64;
    int* sndrow    = (int*)ws; ws += sizeof(int)*N_EDGES;
    int* row_ptr   = (int*)ws; ws += sizeof(int)*(N_NODES+1);
    int* counts    = (int*)ws; ws += sizeof(int)*N_NODES;   // zero region start
    int* cursor    = (int*)ws; ws += sizeof(int)*N_NODES;
    int* scnt      = (int*)ws; ws += sizeof(int)*16;
    int* scur      = (int*)ws; ws += sizeof(int)*16;
    int* sptr      = (int*)ws; ws += sizeof(int)*16;
    int* psptr     = (int*)ws; ws += sizeof(int)*16;
    int* perm      = (int*)ws; ws += sizeof(int)*N_NODES;
    int* inv       = (int*)ws; ws += sizeof(int)*N_NODES;
    int* specS     = (int*)ws; ws += sizeof(int)*N_NODES;
    int* pn        = (int*)ws; ws += sizeof(int)*N_NODES;
    int* tile_spec = (int*)ws; ws += sizeof(int)*NT_MAX;

    SetupArgs sa;
    sa.vectors = vectors; sa.spec = spec; sa.senders = senders; sa.receivers = receivers;
    sa.embW = embW; sa.rW2 = rW2; sa.linW = linW; sa.scW = scW;
    sa.WBlin0 = WBlin0; sa.WBsc0 = WBsc0; sa.W2T0 = W2T0;
    sa.zero_base = counts;
    sa.counts = counts; sa.cursor = cursor; sa.scnt = scnt; sa.scur = scur;
    sa.sptr = sptr; sa.psptr = psptr; sa.tile_spec = tile_spec;
    sa.perm = perm; sa.inv = inv; sa.specS = specS; sa.pn = pn;
    sa.row_ptr = row_ptr; sa.sndrow = sndrow;
    sa.basis_pos = basis_pos; sa.fB0 = fB0;

    MainArgs ma;
    ma.row_ptr = row_ptr; ma.sndrow = sndrow; ma.pn = pn;
    ma.rw0 = rw0;
    ma.WBlin0 = WBlin0; ma.WBsc0 = WBsc0;
    ma.tile_spec = tile_spec; ma.scnt = scnt; ma.sptr = sptr; ma.psptr = psptr; ma.perm = perm;
    ma.prodc = prodc; ma.ro0 = ro0; ma.ro1W1 = ro1W1; ma.ro1W2 = ro1W2;
    ma.fB0 = fB0; ma.fB1 = fB1; ma.aggB0 = aggB0;
    ma.out = out;

    void* sp[] = { &sa };
    hipLaunchCooperativeKernel((void*)k_setup, dim3(CBLK), dim3(256), sp, 0, stream);

    k_rw<<<ETILES, 256, 0, stream>>>(basis_pos, rW1, rb1, W2T0, rw0);

    void* mp[] = { &ma };
    hipLaunchCooperativeKernel((void*)k_main, dim3(CBLK), dim3(256), mp, 0, stream);
}

// Round 17
// 361.811 us; speedup vs baseline: 2.2509x; 2.2509x over previous
//
#include <hip/hip_runtime.h>
#include <math.h>
#include <stdint.h>

#define N_NODES 10000
#define N_EDGES 160000
#define F 128
#define NB 8
#define HR 64
#define NSPEC 10
#define PI_F 3.14159265358979323846f
#define NPAD 10160
#define NT_MAX 635
#define ETILES 2500

typedef unsigned short ushort_t;
typedef __attribute__((ext_vector_type(8))) short short8;
typedef __attribute__((ext_vector_type(4))) float f32x4;

__device__ __forceinline__ float silu_f(float x){ return x / (1.f + expf(-x)); }
__device__ __forceinline__ float bfu(ushort_t u) {
    union { unsigned int i; float f; } v; v.i = ((unsigned int)u) << 16; return v.f;
}
__device__ __forceinline__ ushort_t f2bf(float f) {
    union { float f; unsigned int i; } v; v.f = f;
    unsigned int x = v.i;
    unsigned int r = (x + 0x7fffu + ((x >> 16) & 1u)) >> 16;
    return (ushort_t)r;
}

// ---- 1: zero counters + convert weights (1984 blocks = exactly CONVTOT threads) ----
__global__ __launch_bounds__(256) void k_conv_zero(
    const float* __restrict__ linW, const float* __restrict__ scW, const float* __restrict__ rW2,
    ushort_t* __restrict__ WBlin0, ushort_t* __restrict__ WBsc0, ushort_t* __restrict__ W2T0,
    int* __restrict__ zero_base)
{
    const int gtid = blockIdx.x*256 + threadIdx.x;
    const int GRID = 1984*256;
    for (int i = gtid; i < 2*N_NODES + 32; i += GRID) zero_base[i] = 0;
    const int LINTOT = 2*NSPEC*16384;
    const int SCTOT  = NSPEC*16384;
    int i = gtid;
    if (i < LINTOT) {
        int mat = i >> 14;
        int r = i & 16383;
        int fo = r >> 7, fi = r & 127;
        WBlin0[(size_t)mat*16384 + fo*128 + fi] =
            f2bf(linW[((size_t)mat*4 + 0)*16384 + fi*128 + fo]);
    } else if (i < LINTOT + SCTOT) {
        int t2 = i - LINTOT;
        int sp = t2 >> 14;
        int r = t2 & 16383;
        int fo = r >> 7, fi = r & 127;
        WBsc0[(size_t)sp*16384 + fo*128 + fi] =
            f2bf(scW[((size_t)(NSPEC + sp)*4 + 0)*16384 + fi*128 + fo]);
    } else if (i < LINTOT + SCTOT + 2*128*64) {
        int t2 = i - LINTOT - SCTOT;
        int l = t2 >> 13; int r = t2 & 8191; int f = r >> 6; int k = r & 63;
        W2T0[t2] = f2bf(rW2[(size_t)l*HR*512 + (size_t)k*512 + 4*f]);
    }
}

// ---- 2: both histograms (raw ids) ----
__global__ void k_hist(const int* __restrict__ spec, const int* __restrict__ recv,
                       int* __restrict__ scnt, int* __restrict__ counts)
{
    int i = blockIdx.x*256 + threadIdx.x;
    if (i < N_EDGES) atomicAdd(&counts[recv[i]], 1);
    if (i < N_NODES) atomicAdd(&scnt[spec[i]], 1);
}

// ---- 3: species scan + tile_spec (serial, tiny) ----
__global__ void k_sscan(const int* __restrict__ scnt, int* __restrict__ sptr,
                        int* __restrict__ psptr, int* __restrict__ tile_spec)
{
    if (threadIdx.x == 0) {
        int acc = 0, pacc = 0;
        for (int s = 0; s < NSPEC; ++s) {
            sptr[s] = acc; psptr[s] = pacc;
            acc += scnt[s];
            pacc += ((scnt[s] + 15) >> 4) << 4;
        }
        sptr[NSPEC] = acc; psptr[NSPEC] = pacc;
        for (int tt = 0; tt < NT_MAX; ++tt) tile_spec[tt] = -1;
        for (int s = 0; s < NSPEC; ++s) {
            int t0 = psptr[s] >> 4;
            int t1 = t0 + ((scnt[s] + 15) >> 4);
            for (int tt = t0; tt < t1; ++tt) tile_spec[tt] = s;
        }
    }
}

// ---- 4: sort fill ----
__global__ void k_sfill(const int* __restrict__ spec, const int* __restrict__ sptr,
                        const int* __restrict__ psptr,
                        int* __restrict__ scur, int* __restrict__ perm,
                        int* __restrict__ inv, int* __restrict__ specS,
                        int* __restrict__ pn)
{
    int n = blockIdx.x*256 + threadIdx.x;
    if (n >= N_NODES) return;
    int s = spec[n];
    int pos = sptr[s] + atomicAdd(&scur[s], 1);
    perm[pos] = n; inv[n] = pos; specS[pos] = s;
    pn[pos] = psptr[s] + (pos - sptr[s]);
}

// ---- 5: row_ptr scan (block 0) + fB0 init (other blocks) ----
__global__ __launch_bounds__(256) void k_scan_init(
    const int* __restrict__ counts, const int* __restrict__ perm, int* __restrict__ row_ptr,
    const int* __restrict__ specS, const int* __restrict__ pn,
    const float* __restrict__ embW, ushort_t* __restrict__ fB0)
{
    const int t = threadIdx.x;
    if (blockIdx.x == 0) {
        __shared__ int ps[256];
        int loc[40];
        int sum = 0;
        int base = t * 40;
        #pragma unroll
        for (int j = 0; j < 40; ++j) {
            int idx = base + j;
            int c = (idx < N_NODES) ? counts[perm[idx]] : 0;
            loc[j] = c; sum += c;
        }
        ps[t] = sum;
        __syncthreads();
        for (int off = 1; off < 256; off <<= 1) {
            int v = (t >= off) ? ps[t-off] : 0;
            __syncthreads();
            ps[t] += v;
            __syncthreads();
        }
        int ex = ps[t] - sum;
        #pragma unroll
        for (int j = 0; j < 40; ++j) {
            int idx = base + j;
            if (idx < N_NODES) row_ptr[idx] = ex;
            ex += loc[j];
        }
        if (t == 255) row_ptr[N_NODES] = ex;
    } else {
        int i = (blockIdx.x - 1)*256 + t;
        if (i < N_NODES*F) {
            int n = i >> 7, f = i & 127;
            fB0[(size_t)pn[n]*128 + f] = f2bf(embW[specS[n]*F + f]);
        }
    }
}

// ---- 6: CSR fill + basis + sender rows ----
__global__ void k_fill_pre(const int* __restrict__ recv, const int* __restrict__ senders,
                           const int* __restrict__ inv, const int* __restrict__ pn,
                           const int* __restrict__ row_ptr, int* __restrict__ cursor,
                           const float* __restrict__ vec,
                           float* __restrict__ basis_pos, int* __restrict__ sndrow)
{
    int e = blockIdx.x*256 + threadIdx.x;
    if (e >= N_EDGES) return;
    int r = inv[recv[e]];
    int q = row_ptr[r] + atomicAdd(&cursor[r], 1);
    sndrow[q] = pn[inv[senders[e]]];
    float x = vec[e*3+0], y = vec[e*3+1], z = vec[e*3+2];
    float rr = sqrtf(x*x + y*y + z*z);
    rr = fmaxf(rr, 1e-9f);
    float rc = fminf(rr, 5.0f);
    float cut = 0.5f * (cosf(PI_F * rc * 0.2f) + 1.f);
    float pref = sqrtf(0.4f) * cut / rr;
    float B[8];
    #pragma unroll
    for (int k = 1; k <= 8; ++k) B[k-1] = pref * sinf(PI_F * 0.2f * (float)k * rr);
    float4* dst = (float4*)(basis_pos + (size_t)q*8);
    dst[0] = make_float4(B[0], B[1], B[2], B[3]);
    dst[1] = make_float4(B[4], B[5], B[6], B[7]);
}

// ---- 7: edge-parallel radial MLP, both layers, coalesced LDS-staged writes ----
__global__ __launch_bounds__(256) void k_rw(
    const float* __restrict__ basis_pos,
    const float* __restrict__ rW1,
    const float* __restrict__ rb1,
    const ushort_t* __restrict__ W2T0,
    ushort_t* __restrict__ rw0)
{
    __shared__ float W1s[2][NB*HR];
    __shared__ float b1s[2][HR];
    __shared__ ushort_t hB[4][16][72];
    __shared__ ushort_t rwS[4][2048];

    const int t = threadIdx.x;
    const int wv = t >> 6;
    const int lane = t & 63;
    const int j64 = lane;
    const int r16 = lane & 15;
    const int quad = lane >> 4;

    W1s[0][t] = rW1[t];       W1s[0][256 + t] = rW1[256 + t];
    W1s[1][t] = rW1[512 + t]; W1s[1][256 + t] = rW1[768 + t];
    if (t < HR) { b1s[0][t] = rb1[t]; b1s[1][t] = rb1[HR + t]; }

    const int p0 = blockIdx.x * 64 + wv * 16;
    __syncthreads();

    for (int l = 0; l < 2; ++l) {
        // phase A: h (bf16) — per-wave private LDS
        #pragma unroll 4
        for (int e = 0; e < 16; ++e) {
            const float4* B4 = (const float4*)(basis_pos + (size_t)(p0 + e)*8);
            float4 x0 = B4[0], x1 = B4[1];
            float a = b1s[l][j64];
            a = fmaf(x0.x, W1s[l][0*HR + j64], a);
            a = fmaf(x0.y, W1s[l][1*HR + j64], a);
            a = fmaf(x0.z, W1s[l][2*HR + j64], a);
            a = fmaf(x0.w, W1s[l][3*HR + j64], a);
            a = fmaf(x1.x, W1s[l][4*HR + j64], a);
            a = fmaf(x1.y, W1s[l][5*HR + j64], a);
            a = fmaf(x1.z, W1s[l][6*HR + j64], a);
            a = fmaf(x1.w, W1s[l][7*HR + j64], a);
            hB[wv][e][j64] = f2bf(a / (1.f + expf(-a)));
        }
        // phase B: MFMA rw = h(16x64) @ W2_l0(64x128) -> LDS (per-wave)
        {
            short8 a0 = *(const short8*)&hB[wv][r16][quad*8];
            short8 a1 = *(const short8*)&hB[wv][r16][32 + quad*8];
            const ushort_t* W2l = W2T0 + l*8192;
            #pragma unroll
            for (int nt = 0; nt < 8; ++nt) {
                const int col = nt*16 + r16;
                short8 b0 = *(const short8*)(W2l + (size_t)col*64 + quad*8);
                short8 b1 = *(const short8*)(W2l + (size_t)col*64 + 32 + quad*8);
                f32x4 c = (f32x4){0.f, 0.f, 0.f, 0.f};
                c = __builtin_amdgcn_mfma_f32_16x16x32_bf16(a0, b0, c, 0, 0, 0);
                c = __builtin_amdgcn_mfma_f32_16x16x32_bf16(a1, b1, c, 0, 0, 0);
                #pragma unroll
                for (int r = 0; r < 4; ++r)
                    rwS[wv][(quad*4 + r)*128 + col] = f2bf(c[r]);
            }
        }
        // coalesced write-out: 16 positions x 128 = 2048 contiguous bf16
        {
            ushort_t* dst = rw0 + (size_t)l*N_EDGES*128 + (size_t)p0*128;
            #pragma unroll
            for (int q = 0; q < 4; ++q)
                *(short8*)(dst + q*512 + lane*8) = *(const short8*)(&rwS[wv][q*512 + lane*8]);
        }
    }
}

// ---- 8: layer 0 fused: per-tile agg + lin GEMM + poly + fB1 + readout0 ----
__global__ __launch_bounds__(256) void k_layer0(
    const int* __restrict__ tile_spec, const int* __restrict__ scnt,
    const int* __restrict__ sptr, const int* __restrict__ psptr,
    const int* __restrict__ perm, const int* __restrict__ row_ptr,
    const int* __restrict__ sndrow,
    const ushort_t* __restrict__ rw0l,
    const ushort_t* __restrict__ fB0,
    const ushort_t* __restrict__ WBlin0,
    const float* __restrict__ prodc, const float* __restrict__ ro0,
    ushort_t* __restrict__ fB1, float* __restrict__ out)
{
    __shared__ ushort_t aggS[16][128];
    __shared__ float redS[16][65];
    const int tile = blockIdx.x;
    const int spec = tile_spec[tile];
    if (spec < 0) return;
    const int t = threadIdx.x;
    const int f = t & 127, mh = t >> 7;
    const int lane = t & 63, wv = t >> 6;
    const int r16 = lane & 15, quad = lane >> 4;

    // agg: thread (f,mh) handles nodes ni = mh, mh+2, ..., mh+14
    const int base_rel = tile*16 - psptr[spec];
    const int cnt = scnt[spec], sbase = sptr[spec];
    #pragma unroll
    for (int ni = mh; ni < 16; ni += 2) {
        const int rel = base_rel + ni;
        float acc = 0.f;
        if (rel < cnt) {
            const int ns = sbase + rel;
            const int pa = row_ptr[ns], pb = row_ptr[ns+1];
            #pragma unroll 4
            for (int p = pa; p < pb; ++p) {
                const float sf = bfu(fB0[(size_t)sndrow[p]*128 + f]);
                const float rl = bfu(rw0l[(size_t)p*128 + f]);
                acc = fmaf(sf, rl, acc);
            }
        }
        aggS[ni][f] = f2bf(acc);
    }
    __syncthreads();

    // GEMM + epilogue
    short8 a[4];
    #pragma unroll
    for (int c = 0; c < 4; ++c)
        a[c] = *(const short8*)&aggS[r16][c*32 + quad*8];
    const ushort_t* Wp = WBlin0 + (size_t)spec*16384;
    const float* pc = prodc + (size_t)spec*3*F;
    float pr[4] = {0.f, 0.f, 0.f, 0.f};
    #pragma unroll
    for (int nt = 0; nt < 2; ++nt) {
        const int col = wv*32 + nt*16 + r16;
        f32x4 acc = (f32x4){0.f, 0.f, 0.f, 0.f};
        #pragma unroll
        for (int c = 0; c < 4; ++c) {
            short8 b = *(const short8*)(Wp + (size_t)col*128 + c*32 + quad*8);
            acc = __builtin_amdgcn_mfma_f32_16x16x32_bf16(a[c], b, acc, 0, 0, 0);
        }
        const float w0 = ro0[col];
        const float p0c = pc[col], p1c = pc[F+col], p2c = pc[2*F+col];
        #pragma unroll
        for (int r = 0; r < 4; ++r) {
            float s = acc[r] * 0.5f;
            float val = s * (p0c + p1c*s + p2c*s*s);
            fB1[((size_t)tile*16 + quad*4 + r)*128 + col] = f2bf(val);
            pr[r] = fmaf(val, w0, pr[r]);
        }
    }
    #pragma unroll
    for (int r = 0; r < 4; ++r) redS[quad*4 + r][wv*16 + r16] = pr[r];
    __syncthreads();
    if (t < 16) {
        int rel = tile*16 + t - psptr[spec];
        if (rel < cnt) {
            float s = 0.f;
            for (int j = 0; j < 64; ++j) s += redS[t][j];
            out[(size_t)perm[sbase + rel]*2 + 0] = s;
        }
    }
}

// ---- 9: layer 1 fused: per-tile agg + lin/sc GEMM + poly + MLP readout1 ----
__global__ __launch_bounds__(256) void k_layer1(
    const int* __restrict__ tile_spec, const int* __restrict__ scnt,
    const int* __restrict__ sptr, const int* __restrict__ psptr,
    const int* __restrict__ perm, const int* __restrict__ row_ptr,
    const int* __restrict__ sndrow,
    const ushort_t* __restrict__ rw1l,
    const ushort_t* __restrict__ fB1,
    const ushort_t* __restrict__ WBlin1, const ushort_t* __restrict__ WBsc0,
    const float* __restrict__ prodc,
    const float* __restrict__ ro1W1, const float* __restrict__ ro1W2,
    float* __restrict__ out)
{
    __shared__ ushort_t aggS[16][128];
    __shared__ float sS[16][132];
    __shared__ float yS[16][17];
    const int tile = blockIdx.x;
    const int spec = tile_spec[tile];
    if (spec < 0) return;
    const int t = threadIdx.x;
    const int f = t & 127, mh = t >> 7;
    const int lane = t & 63, wv = t >> 6;
    const int r16 = lane & 15, quad = lane >> 4;

    const int base_rel = tile*16 - psptr[spec];
    const int cnt = scnt[spec], sbase = sptr[spec];
    #pragma unroll
    for (int ni = mh; ni < 16; ni += 2) {
        const int rel = base_rel + ni;
        float acc = 0.f;
        if (rel < cnt) {
            const int ns = sbase + rel;
            const int pa = row_ptr[ns], pb = row_ptr[ns+1];
            #pragma unroll 4
            for (int p = pa; p < pb; ++p) {
                const float sf = bfu(fB1[(size_t)sndrow[p]*128 + f]);
                const float rl = bfu(rw1l[(size_t)p*128 + f]);
                acc = fmaf(sf, rl, acc);
            }
        }
        aggS[ni][f] = f2bf(acc);
    }
    __syncthreads();

    const ushort_t* Fp = fB1 + (size_t)tile*16*128;
    const ushort_t* Wl = WBlin1 + (size_t)spec*16384;
    const ushort_t* Ws = WBsc0  + (size_t)spec*16384;
    const float* pc = prodc + ((size_t)NSPEC + spec)*3*F;
    short8 a1[4], a2[4];
    #pragma unroll
    for (int c = 0; c < 4; ++c) {
        a1[c] = *(const short8*)&aggS[r16][c*32 + quad*8];
        a2[c] = *(const short8*)(Fp + (size_t)r16*128 + c*32 + quad*8);
    }
    #pragma unroll
    for (int nt = 0; nt < 2; ++nt) {
        const int col = wv*32 + nt*16 + r16;
        f32x4 accl = (f32x4){0.f, 0.f, 0.f, 0.f};
        f32x4 accs = (f32x4){0.f, 0.f, 0.f, 0.f};
        #pragma unroll
        for (int c = 0; c < 4; ++c) {
            short8 bl = *(const short8*)(Wl + (size_t)col*128 + c*32 + quad*8);
            short8 bs = *(const short8*)(Ws + (size_t)col*128 + c*32 + quad*8);
            accl = __builtin_amdgcn_mfma_f32_16x16x32_bf16(a1[c], bl, accl, 0, 0, 0);
            accs = __builtin_amdgcn_mfma_f32_16x16x32_bf16(a2[c], bs, accs, 0, 0, 0);
        }
        const float p0c = pc[col], p1c = pc[F+col], p2c = pc[2*F+col];
        #pragma unroll
        for (int r = 0; r < 4; ++r) {
            float s = accl[r] * 0.5f;
            sS[quad*4 + r][col] = s * (p0c + p1c*s + p2c*s*s) + accs[r];
        }
    }
    __syncthreads();
    {
        const int node = t >> 4, c = t & 15;
        float a = 0.f;
        #pragma unroll 8
        for (int g = 0; g < F; ++g) a = fmaf(sS[node][g], ro1W1[g*16 + c], a);
        a = silu_f(a);
        yS[node][c] = a * ro1W2[c];
    }
    __syncthreads();
    if (t < 16) {
        int rel = tile*16 + t - psptr[spec];
        if (rel < cnt) {
            float s = 0.f;
            #pragma unroll
            for (int j = 0; j < 16; ++j) s += yS[t][j];
            out[(size_t)perm[sbase + rel]*2 + 1] = s;
        }
    }
}

extern "C" void kernel_launch(void* const* d_in, const int* in_sizes, int n_in,
                              void* d_out, int out_size, void* d_ws, size_t ws_size,
                              hipStream_t stream)
{
    (void)in_sizes; (void)n_in; (void)out_size; (void)ws_size;
    const float* vectors   = (const float*)d_in[0];
    const int*   spec      = (const int*)d_in[1];
    const int*   senders   = (const int*)d_in[2];
    const int*   receivers = (const int*)d_in[3];
    const float* embW      = (const float*)d_in[4];
    const float* rW1       = (const float*)d_in[5];
    const float* rb1       = (const float*)d_in[6];
    const float* rW2       = (const float*)d_in[7];
    const float* linW      = (const float*)d_in[8];
    const float* prodc     = (const float*)d_in[9];
    const float* scW       = (const float*)d_in[10];
    const float* ro0       = (const float*)d_in[11];
    const float* ro1W1     = (const float*)d_in[12];
    const float* ro1W2     = (const float*)d_in[13];
    float* out = (float*)d_out;

    char* ws = (char*)d_ws;
    float*    basis_pos = (float*)ws;    ws += sizeof(float)*(size_t)N_EDGES*8;
    ushort_t* rw0       = (ushort_t*)ws; ws += sizeof(ushort_t)*(size_t)2*N_EDGES*128;
    ushort_t* fB0       = (ushort_t*)ws; ws += sizeof(ushort_t)*(size_t)NPAD*128;
    ushort_t* fB1       = (ushort_t*)ws; ws += sizeof(ushort_t)*(size_t)NPAD*128;
    ushort_t* WBlin0    = (ushort_t*)ws; ws += sizeof(ushort_t)*(size_t)2*NSPEC*16384;
    ushort_t* WBsc0     = (ushort_t*)ws; ws += sizeof(ushort_t)*(size_t)NSPEC*16384;
    ushort_t* W2T0      = (ushort_t*)ws; ws += sizeof(ushort_t)*(size_t)2*128*64;
    int* sndrow    = (int*)ws; ws += sizeof(int)*N_EDGES;
    int* row_ptr   = (int*)ws; ws += sizeof(int)*(N_NODES+1);
    int* counts    = (int*)ws; ws += sizeof(int)*N_NODES;   // zero region start
    int* cursor    = (int*)ws; ws += sizeof(int)*N_NODES;
    int* scnt      = (int*)ws; ws += sizeof(int)*16;
    int* scur      = (int*)ws; ws += sizeof(int)*16;
    int* sptr      = (int*)ws; ws += sizeof(int)*16;
    int* psptr     = (int*)ws; ws += sizeof(int)*16;
    int* perm      = (int*)ws; ws += sizeof(int)*N_NODES;
    int* inv       = (int*)ws; ws += sizeof(int)*N_NODES;
    int* specS     = (int*)ws; ws += sizeof(int)*N_NODES;
    int* pn        = (int*)ws; ws += sizeof(int)*N_NODES;
    int* tile_spec = (int*)ws; ws += sizeof(int)*NT_MAX;

    const int EB = (N_EDGES + 255)/256;

    k_conv_zero<<<1984, 256, 0, stream>>>(linW, scW, rW2, WBlin0, WBsc0, W2T0, counts);
    k_hist<<<EB, 256, 0, stream>>>(spec, receivers, scnt, counts);
    k_sscan<<<1, 64, 0, stream>>>(scnt, sptr, psptr, tile_spec);
    k_sfill<<<(N_NODES + 255)/256, 256, 0, stream>>>(spec, sptr, psptr, scur, perm, inv, specS, pn);
    k_scan_init<<<1 + (N_NODES*F + 255)/256, 256, 0, stream>>>(counts, perm, row_ptr, specS, pn, embW, fB0);
    k_fill_pre<<<EB, 256, 0, stream>>>(receivers, senders, inv, pn, row_ptr, cursor,
                                       vectors, basis_pos, sndrow);
    k_rw<<<ETILES, 256, 0, stream>>>(basis_pos, rW1, rb1, W2T0, rw0);

    k_layer0<<<NT_MAX, 256, 0, stream>>>(tile_spec, scnt, sptr, psptr, perm, row_ptr, sndrow,
        rw0, fB0, WBlin0, prodc, ro0, fB1, out);
    k_layer1<<<NT_MAX, 256, 0, stream>>>(tile_spec, scnt, sptr, psptr, perm, row_ptr, sndrow,
        rw0 + (size_t)N_EDGES*128, fB1, WBlin0 + (size_t)NSPEC*16384, WBsc0,
        prodc, ro1W1, ro1W2, out);
}

// Round 18
// 314.222 us; speedup vs baseline: 2.5918x; 1.1514x over previous
//
#include <hip/hip_runtime.h>
#include <math.h>
#include <stdint.h>

#define N_NODES 10000
#define N_EDGES 160000
#define F 128
#define NB 8
#define HR 64
#define NSPEC 10
#define PI_F 3.14159265358979323846f
#define NPAD 10160
#define NT_MAX 635
#define ETILES 2500

typedef unsigned short ushort_t;
typedef __attribute__((ext_vector_type(8))) short short8;
typedef __attribute__((ext_vector_type(4))) float f32x4;

__device__ __forceinline__ float silu_f(float x){ return x / (1.f + expf(-x)); }
__device__ __forceinline__ float bfu(ushort_t u) {
    union { unsigned int i; float f; } v; v.i = ((unsigned int)u) << 16; return v.f;
}
__device__ __forceinline__ ushort_t f2bf(float f) {
    union { float f; unsigned int i; } v; v.f = f;
    unsigned int x = v.i;
    unsigned int r = (x + 0x7fffu + ((x >> 16) & 1u)) >> 16;
    return (ushort_t)r;
}

// ---- 1: zero counters + convert weights ----
__global__ __launch_bounds__(256) void k_conv_zero(
    const float* __restrict__ linW, const float* __restrict__ scW, const float* __restrict__ rW2,
    ushort_t* __restrict__ WBlin0, ushort_t* __restrict__ WBsc0, ushort_t* __restrict__ W2T0,
    int* __restrict__ zero_base)
{
    const int gtid = blockIdx.x*256 + threadIdx.x;
    const int GRID = 1984*256;
    for (int i = gtid; i < 2*N_NODES + 32; i += GRID) zero_base[i] = 0;
    const int LINTOT = 2*NSPEC*16384;
    const int SCTOT  = NSPEC*16384;
    int i = gtid;
    if (i < LINTOT) {
        int mat = i >> 14;
        int r = i & 16383;
        int fo = r >> 7, fi = r & 127;
        WBlin0[(size_t)mat*16384 + fo*128 + fi] =
            f2bf(linW[((size_t)mat*4 + 0)*16384 + fi*128 + fo]);
    } else if (i < LINTOT + SCTOT) {
        int t2 = i - LINTOT;
        int sp = t2 >> 14;
        int r = t2 & 16383;
        int fo = r >> 7, fi = r & 127;
        WBsc0[(size_t)sp*16384 + fo*128 + fi] =
            f2bf(scW[((size_t)(NSPEC + sp)*4 + 0)*16384 + fi*128 + fo]);
    } else if (i < LINTOT + SCTOT + 2*128*64) {
        int t2 = i - LINTOT - SCTOT;
        int l = t2 >> 13; int r = t2 & 8191; int f = r >> 6; int k = r & 63;
        W2T0[t2] = f2bf(rW2[(size_t)l*HR*512 + (size_t)k*512 + 4*f]);
    }
}

// ---- 2: both histograms (raw ids) ----
__global__ void k_hist(const int* __restrict__ spec, const int* __restrict__ recv,
                       int* __restrict__ scnt, int* __restrict__ counts)
{
    int i = blockIdx.x*256 + threadIdx.x;
    if (i < N_EDGES) atomicAdd(&counts[recv[i]], 1);
    if (i < N_NODES) atomicAdd(&scnt[spec[i]], 1);
}

// ---- 3: sort fill with per-block local species scan; block 0 publishes sptr/psptr ----
__global__ __launch_bounds__(256) void k_sfill(
    const int* __restrict__ spec, const int* __restrict__ scnt,
    int* __restrict__ sptr, int* __restrict__ psptr,
    int* __restrict__ scur, int* __restrict__ perm,
    int* __restrict__ inv, int* __restrict__ specS, int* __restrict__ pn)
{
    __shared__ int sptrL[NSPEC+1], psptrL[NSPEC+1];
    const int t = threadIdx.x;
    if (t == 0) {
        int acc = 0, pacc = 0;
        for (int s = 0; s < NSPEC; ++s) {
            sptrL[s] = acc; psptrL[s] = pacc;
            acc += scnt[s];
            pacc += ((scnt[s] + 15) >> 4) << 4;
        }
        sptrL[NSPEC] = acc; psptrL[NSPEC] = pacc;
        if (blockIdx.x == 0) {
            for (int s = 0; s <= NSPEC; ++s) { sptr[s] = sptrL[s]; psptr[s] = psptrL[s]; }
        }
    }
    __syncthreads();
    int n = blockIdx.x*256 + t;
    if (n >= N_NODES) return;
    int s = spec[n];
    int pos = sptrL[s] + atomicAdd(&scur[s], 1);
    perm[pos] = n; inv[n] = pos; specS[pos] = s;
    pn[pos] = psptrL[s] + (pos - sptrL[s]);
}

// ---- 4: row_ptr scan (block 0) + fB0 init (other blocks) ----
__global__ __launch_bounds__(256) void k_scan_init(
    const int* __restrict__ counts, const int* __restrict__ perm, int* __restrict__ row_ptr,
    const int* __restrict__ specS, const int* __restrict__ pn,
    const float* __restrict__ embW, ushort_t* __restrict__ fB0)
{
    const int t = threadIdx.x;
    if (blockIdx.x == 0) {
        __shared__ int ps[256];
        int loc[40];
        int sum = 0;
        int base = t * 40;
        #pragma unroll
        for (int j = 0; j < 40; ++j) {
            int idx = base + j;
            int c = (idx < N_NODES) ? counts[perm[idx]] : 0;
            loc[j] = c; sum += c;
        }
        ps[t] = sum;
        __syncthreads();
        for (int off = 1; off < 256; off <<= 1) {
            int v = (t >= off) ? ps[t-off] : 0;
            __syncthreads();
            ps[t] += v;
            __syncthreads();
        }
        int ex = ps[t] - sum;
        #pragma unroll
        for (int j = 0; j < 40; ++j) {
            int idx = base + j;
            if (idx < N_NODES) row_ptr[idx] = ex;
            ex += loc[j];
        }
        if (t == 255) row_ptr[N_NODES] = ex;
    } else {
        int i = (blockIdx.x - 1)*256 + t;
        if (i < N_NODES*F) {
            int n = i >> 7, f = i & 127;
            fB0[(size_t)pn[n]*128 + f] = f2bf(embW[specS[n]*F + f]);
        }
    }
}

// ---- 5: CSR fill + basis + sender rows ----
__global__ void k_fill_pre(const int* __restrict__ recv, const int* __restrict__ senders,
                           const int* __restrict__ inv, const int* __restrict__ pn,
                           const int* __restrict__ row_ptr, int* __restrict__ cursor,
                           const float* __restrict__ vec,
                           float* __restrict__ basis_pos, int* __restrict__ sndrow)
{
    int e = blockIdx.x*256 + threadIdx.x;
    if (e >= N_EDGES) return;
    int r = inv[recv[e]];
    int q = row_ptr[r] + atomicAdd(&cursor[r], 1);
    sndrow[q] = pn[inv[senders[e]]];
    float x = vec[e*3+0], y = vec[e*3+1], z = vec[e*3+2];
    float rr = sqrtf(x*x + y*y + z*z);
    rr = fmaxf(rr, 1e-9f);
    float rc = fminf(rr, 5.0f);
    float cut = 0.5f * (cosf(PI_F * rc * 0.2f) + 1.f);
    float pref = sqrtf(0.4f) * cut / rr;
    float B[8];
    #pragma unroll
    for (int k = 1; k <= 8; ++k) B[k-1] = pref * sinf(PI_F * 0.2f * (float)k * rr);
    float4* dst = (float4*)(basis_pos + (size_t)q*8);
    dst[0] = make_float4(B[0], B[1], B[2], B[3]);
    dst[1] = make_float4(B[4], B[5], B[6], B[7]);
}

// ---- 6: edge-parallel radial MLP, both layers, coalesced LDS-staged writes ----
__global__ __launch_bounds__(256) void k_rw(
    const float* __restrict__ basis_pos,
    const float* __restrict__ rW1,
    const float* __restrict__ rb1,
    const ushort_t* __restrict__ W2T0,
    ushort_t* __restrict__ rw0)
{
    __shared__ float W1s[2][NB*HR];
    __shared__ float b1s[2][HR];
    __shared__ ushort_t hB[4][16][72];
    __shared__ ushort_t rwS[4][2048];

    const int t = threadIdx.x;
    const int wv = t >> 6;
    const int lane = t & 63;
    const int j64 = lane;
    const int r16 = lane & 15;
    const int quad = lane >> 4;

    W1s[0][t] = rW1[t];       W1s[0][256 + t] = rW1[256 + t];
    W1s[1][t] = rW1[512 + t]; W1s[1][256 + t] = rW1[768 + t];
    if (t < HR) { b1s[0][t] = rb1[t]; b1s[1][t] = rb1[HR + t]; }

    const int p0 = blockIdx.x * 64 + wv * 16;
    __syncthreads();

    for (int l = 0; l < 2; ++l) {
        #pragma unroll 4
        for (int e = 0; e < 16; ++e) {
            const float4* B4 = (const float4*)(basis_pos + (size_t)(p0 + e)*8);
            float4 x0 = B4[0], x1 = B4[1];
            float a = b1s[l][j64];
            a = fmaf(x0.x, W1s[l][0*HR + j64], a);
            a = fmaf(x0.y, W1s[l][1*HR + j64], a);
            a = fmaf(x0.z, W1s[l][2*HR + j64], a);
            a = fmaf(x0.w, W1s[l][3*HR + j64], a);
            a = fmaf(x1.x, W1s[l][4*HR + j64], a);
            a = fmaf(x1.y, W1s[l][5*HR + j64], a);
            a = fmaf(x1.z, W1s[l][6*HR + j64], a);
            a = fmaf(x1.w, W1s[l][7*HR + j64], a);
            hB[wv][e][j64] = f2bf(a / (1.f + expf(-a)));
        }
        {
            short8 a0 = *(const short8*)&hB[wv][r16][quad*8];
            short8 a1 = *(const short8*)&hB[wv][r16][32 + quad*8];
            const ushort_t* W2l = W2T0 + l*8192;
            #pragma unroll
            for (int nt = 0; nt < 8; ++nt) {
                const int col = nt*16 + r16;
                short8 b0 = *(const short8*)(W2l + (size_t)col*64 + quad*8);
                short8 b1 = *(const short8*)(W2l + (size_t)col*64 + 32 + quad*8);
                f32x4 c = (f32x4){0.f, 0.f, 0.f, 0.f};
                c = __builtin_amdgcn_mfma_f32_16x16x32_bf16(a0, b0, c, 0, 0, 0);
                c = __builtin_amdgcn_mfma_f32_16x16x32_bf16(a1, b1, c, 0, 0, 0);
                #pragma unroll
                for (int r = 0; r < 4; ++r)
                    rwS[wv][(quad*4 + r)*128 + col] = f2bf(c[r]);
            }
        }
        {
            ushort_t* dst = rw0 + (size_t)l*N_EDGES*128 + (size_t)p0*128;
            #pragma unroll
            for (int q = 0; q < 4; ++q)
                *(short8*)(dst + q*512 + lane*8) = *(const short8*)(&rwS[wv][q*512 + lane*8]);
        }
    }
}

// ---- 7: per-node m=0 aggregation (2 nodes/block, high occupancy) ----
__global__ __launch_bounds__(256) void k_agg0(
    const int* __restrict__ row_ptr,
    const int* __restrict__ sndrow,
    const int* __restrict__ pn,
    const ushort_t* __restrict__ rw0l,
    const ushort_t* __restrict__ fB_in,
    ushort_t* __restrict__ aggB0)
{
    const int t = threadIdx.x;
    const int n = blockIdx.x*2 + (t >> 7);
    const int f = t & 127;
    const int p0 = row_ptr[n], p1 = row_ptr[n+1];
    float acc = 0.f;
    #pragma unroll 4
    for (int p = p0; p < p1; ++p) {
        const float sf = bfu(fB_in[(size_t)sndrow[p]*128 + f]);
        const float rl = bfu(rw0l[(size_t)p*128 + f]);
        acc = fmaf(sf, rl, acc);
    }
    aggB0[(size_t)pn[n]*128 + f] = f2bf(acc);
}

// ---- tile -> species from psptr (10-step scan) ----
__device__ __forceinline__ int tile_to_spec(const int* __restrict__ psptr, int tile)
{
    int spec = 0;
    const int row = tile*16;
    #pragma unroll
    for (int s = 1; s < NSPEC; ++s)
        if (row >= psptr[s]) spec = s;
    return spec;
}

// ---- 8: layer-0 gemm+epi: lin GEMM + poly + fB1 + readout0 ----
__global__ __launch_bounds__(256) void k_gemm_epi0(
    const ushort_t* __restrict__ aggB0,
    const ushort_t* __restrict__ WBlin0,
    const int* __restrict__ scnt, const int* __restrict__ sptr,
    const int* __restrict__ psptr, const int* __restrict__ perm,
    const float* __restrict__ prodc, const float* __restrict__ ro0,
    ushort_t* __restrict__ fB1, float* __restrict__ out)
{
    __shared__ float redS[16][65];
    const int tile = blockIdx.x;
    const int spec = tile_to_spec(psptr, tile);
    const int t = threadIdx.x;
    const int lane = t & 63;
    const int wv = t >> 6;
    const int r16 = lane & 15;
    const int quad = lane >> 4;

    const ushort_t* Ap = aggB0 + (size_t)tile*16*128;
    const ushort_t* Wp = WBlin0 + (size_t)spec*16384;
    const float* pc = prodc + (size_t)spec*3*F;

    short8 a[4];
    #pragma unroll
    for (int c = 0; c < 4; ++c)
        a[c] = *(const short8*)(Ap + (size_t)r16*128 + c*32 + quad*8);

    float pr[4] = {0.f, 0.f, 0.f, 0.f};
    #pragma unroll
    for (int nt = 0; nt < 2; ++nt) {
        const int col = wv*32 + nt*16 + r16;
        f32x4 acc = (f32x4){0.f, 0.f, 0.f, 0.f};
        #pragma unroll
        for (int c = 0; c < 4; ++c) {
            short8 b = *(const short8*)(Wp + (size_t)col*128 + c*32 + quad*8);
            acc = __builtin_amdgcn_mfma_f32_16x16x32_bf16(a[c], b, acc, 0, 0, 0);
        }
        const float w0 = ro0[col];
        const float p0c = pc[col], p1c = pc[F+col], p2c = pc[2*F+col];
        #pragma unroll
        for (int r = 0; r < 4; ++r) {
            float s = acc[r] * 0.5f;
            float val = s * (p0c + p1c*s + p2c*s*s);
            fB1[((size_t)tile*16 + quad*4 + r)*128 + col] = f2bf(val);
            pr[r] = fmaf(val, w0, pr[r]);
        }
    }
    #pragma unroll
    for (int r = 0; r < 4; ++r) redS[quad*4 + r][wv*16 + r16] = pr[r];
    __syncthreads();
    if (t < 16) {
        int rel = tile*16 + t - psptr[spec];
        if (rel >= 0 && rel < scnt[spec]) {
            float s = 0.f;
            for (int j = 0; j < 64; ++j) s += redS[t][j];
            out[(size_t)perm[sptr[spec] + rel]*2 + 0] = s;
        }
    }
}

// ---- 9: layer-1 gemm+epi: lin+sc GEMM + poly + MLP readout1 ----
__global__ __launch_bounds__(256) void k_gemm_epi1(
    const ushort_t* __restrict__ aggB0,
    const ushort_t* __restrict__ fB1,
    const ushort_t* __restrict__ WBlin1, const ushort_t* __restrict__ WBsc0,
    const int* __restrict__ scnt, const int* __restrict__ sptr,
    const int* __restrict__ psptr, const int* __restrict__ perm,
    const float* __restrict__ prodc,
    const float* __restrict__ ro1W1, const float* __restrict__ ro1W2,
    float* __restrict__ out)
{
    __shared__ float sS[16][132];
    __shared__ float yS[16][17];
    const int tile = blockIdx.x;
    const int spec = tile_to_spec(psptr, tile);
    const int t = threadIdx.x;
    const int lane = t & 63;
    const int wv = t >> 6;
    const int r16 = lane & 15;
    const int quad = lane >> 4;

    const ushort_t* Ap = aggB0 + (size_t)tile*16*128;
    const ushort_t* Fp = fB1   + (size_t)tile*16*128;
    const ushort_t* Wl = WBlin1 + (size_t)spec*16384;
    const ushort_t* Ws = WBsc0  + (size_t)spec*16384;
    const float* pc = prodc + ((size_t)NSPEC + spec)*3*F;

    short8 a1[4], a2[4];
    #pragma unroll
    for (int c = 0; c < 4; ++c) {
        a1[c] = *(const short8*)(Ap + (size_t)r16*128 + c*32 + quad*8);
        a2[c] = *(const short8*)(Fp + (size_t)r16*128 + c*32 + quad*8);
    }
    #pragma unroll
    for (int nt = 0; nt < 2; ++nt) {
        const int col = wv*32 + nt*16 + r16;
        f32x4 accl = (f32x4){0.f, 0.f, 0.f, 0.f};
        f32x4 accs = (f32x4){0.f, 0.f, 0.f, 0.f};
        #pragma unroll
        for (int c = 0; c < 4; ++c) {
            short8 bl = *(const short8*)(Wl + (size_t)col*128 + c*32 + quad*8);
            short8 bs = *(const short8*)(Ws + (size_t)col*128 + c*32 + quad*8);
            accl = __builtin_amdgcn_mfma_f32_16x16x32_bf16(a1[c], bl, accl, 0, 0, 0);
            accs = __builtin_amdgcn_mfma_f32_16x16x32_bf16(a2[c], bs, accs, 0, 0, 0);
        }
        const float p0c = pc[col], p1c = pc[F+col], p2c = pc[2*F+col];
        #pragma unroll
        for (int r = 0; r < 4; ++r) {
            float s = accl[r] * 0.5f;
            sS[quad*4 + r][col] = s * (p0c + p1c*s + p2c*s*s) + accs[r];
        }
    }
    __syncthreads();
    {
        const int node = t >> 4, c = t & 15;
        float a = 0.f;
        #pragma unroll 8
        for (int g = 0; g < F; ++g) a = fmaf(sS[node][g], ro1W1[g*16 + c], a);
        a = silu_f(a);
        yS[node][c] = a * ro1W2[c];
    }
    __syncthreads();
    if (t < 16) {
        int rel = tile*16 + t - psptr[spec];
        if (rel >= 0 && rel < scnt[spec]) {
            float s = 0.f;
            #pragma unroll
            for (int j = 0; j < 16; ++j) s += yS[t][j];
            out[(size_t)perm[sptr[spec] + rel]*2 + 1] = s;
        }
    }
}

extern "C" void kernel_launch(void* const* d_in, const int* in_sizes, int n_in,
                              void* d_out, int out_size, void* d_ws, size_t ws_size,
                              hipStream_t stream)
{
    (void)in_sizes; (void)n_in; (void)out_size; (void)ws_size;
    const float* vectors   = (const float*)d_in[0];
    const int*   spec      = (const int*)d_in[1];
    const int*   senders   = (const int*)d_in[2];
    const int*   receivers = (const int*)d_in[3];
    const float* embW      = (const float*)d_in[4];
    const float* rW1       = (const float*)d_in[5];
    const float* rb1       = (const float*)d_in[6];
    const float* rW2       = (const float*)d_in[7];
    const float* linW      = (const float*)d_in[8];
    const float* prodc     = (const float*)d_in[9];
    const float* scW       = (const float*)d_in[10];
    const float* ro0       = (const float*)d_in[11];
    const float* ro1W1     = (const float*)d_in[12];
    const float* ro1W2     = (const float*)d_in[13];
    float* out = (float*)d_out;

    char* ws = (char*)d_ws;
    float*    basis_pos = (float*)ws;    ws += sizeof(float)*(size_t)N_EDGES*8;
    ushort_t* rw0       = (ushort_t*)ws; ws += sizeof(ushort_t)*(size_t)2*N_EDGES*128;
    ushort_t* fB0       = (ushort_t*)ws; ws += sizeof(ushort_t)*(size_t)NPAD*128;
    ushort_t* fB1       = (ushort_t*)ws; ws += sizeof(ushort_t)*(size_t)NPAD*128;
    ushort_t* aggB0     = (ushort_t*)ws; ws += sizeof(ushort_t)*(size_t)NPAD*128;
    ushort_t* WBlin0    = (ushort_t*)ws; ws += sizeof(ushort_t)*(size_t)2*NSPEC*16384;
    ushort_t* WBsc0     = (ushort_t*)ws; ws += sizeof(ushort_t)*(size_t)NSPEC*16384;
    ushort_t* W2T0      = (ushort_t*)ws; ws += sizeof(ushort_t)*(size_t)2*128*64;
    int* sndrow    = (int*)ws; ws += sizeof(int)*N_EDGES;
    int* row_ptr   = (int*)ws; ws += sizeof(int)*(N_NODES+1);
    int* counts    = (int*)ws; ws += sizeof(int)*N_NODES;   // zero region start
    int* cursor    = (int*)ws; ws += sizeof(int)*N_NODES;
    int* scnt      = (int*)ws; ws += sizeof(int)*16;
    int* scur      = (int*)ws; ws += sizeof(int)*16;
    int* sptr      = (int*)ws; ws += sizeof(int)*16;
    int* psptr     = (int*)ws; ws += sizeof(int)*16;
    int* perm      = (int*)ws; ws += sizeof(int)*N_NODES;
    int* inv       = (int*)ws; ws += sizeof(int)*N_NODES;
    int* specS     = (int*)ws; ws += sizeof(int)*N_NODES;
    int* pn        = (int*)ws; ws += sizeof(int)*N_NODES;

    const int EB = (N_EDGES + 255)/256;

    k_conv_zero<<<1984, 256, 0, stream>>>(linW, scW, rW2, WBlin0, WBsc0, W2T0, counts);
    k_hist<<<EB, 256, 0, stream>>>(spec, receivers, scnt, counts);
    k_sfill<<<(N_NODES + 255)/256, 256, 0, stream>>>(spec, scnt, sptr, psptr, scur,
                                                     perm, inv, specS, pn);
    k_scan_init<<<1 + (N_NODES*F + 255)/256, 256, 0, stream>>>(counts, perm, row_ptr,
                                                               specS, pn, embW, fB0);
    k_fill_pre<<<EB, 256, 0, stream>>>(receivers, senders, inv, pn, row_ptr, cursor,
                                       vectors, basis_pos, sndrow);
    k_rw<<<ETILES, 256, 0, stream>>>(basis_pos, rW1, rb1, W2T0, rw0);

    // layer 0
    k_agg0<<<N_NODES/2, 256, 0, stream>>>(row_ptr, sndrow, pn, rw0, fB0, aggB0);
    k_gemm_epi0<<<NT_MAX, 256, 0, stream>>>(aggB0, WBlin0, scnt, sptr, psptr, perm,
                                            prodc, ro0, fB1, out);
    // layer 1
    k_agg0<<<N_NODES/2, 256, 0, stream>>>(row_ptr, sndrow, pn, rw0 + (size_t)N_EDGES*128, fB1, aggB0);
    k_gemm_epi1<<<NT_MAX, 256, 0, stream>>>(aggB0, fB1, WBlin0 + (size_t)NSPEC*16384, WBsc0,
                                            scnt, sptr, psptr, perm, prodc, ro1W1, ro1W2, out);
}